// Round 7
// baseline (127.220 us; speedup 1.0000x reference)
//
#include <hip/hip_runtime.h>
#include <math.h>

#define B_ 4
#define N_ 8192
#define C_ 128
#define CN_ 64
#define M_ 32

#define ROR1 0x121
#define ROR2 0x122
#define ROR4 0x124
#define ROR8 0x128

typedef float f4 __attribute__((ext_vector_type(4)));
typedef float f2 __attribute__((ext_vector_type(2)));

__device__ __forceinline__ f4 ld4(const float* p) {
    return *(const f4*)p;
}

template<int CTRL>
__device__ __forceinline__ float dpp_add(float x) {
    int y = __builtin_amdgcn_update_dpp(0, __float_as_int(x), CTRL, 0xF, 0xF, true);
    return x + __int_as_float(y);
}
template<int CTRL>
__device__ __forceinline__ float dpp_max(float x) {
    int y = __builtin_amdgcn_update_dpp(0, __float_as_int(x), CTRL, 0xF, 0xF, true);
    return fmaxf(x, __int_as_float(y));
}
__device__ __forceinline__ float red16_add(float x) {
    return dpp_add<ROR1>(dpp_add<ROR2>(dpp_add<ROR4>(dpp_add<ROR8>(x))));
}

// ================= k1: [0,1024) vsum partials | [1024,2048) a/kb rows =================
__global__ __launch_bounds__(256) void k1(const float* __restrict__ q,
                                          const float* __restrict__ k,
                                          const float* __restrict__ v,
                                          const float* __restrict__ Wq,
                                          const float* __restrict__ Wk,
                                          const float* __restrict__ w1,
                                          float* __restrict__ vsum_part,
                                          float* __restrict__ a_ws,
                                          float* __restrict__ kb_ws) {
    int g = blockIdx.x;
    int t = threadIdx.x;
    if (g < 1024) {
        // ---- vsum partial: 256 chunks per b, 32 rows each ----
        int b = g >> 8;
        int chunk = g & 255;
        const float* vb = v + ((size_t)b * N_ + (size_t)chunk * 32) * C_;
        int c4 = t & 31, h = t >> 5;          // 8 row-groups
        f4 acc = (f4){0.f, 0.f, 0.f, 0.f};
#pragma unroll
        for (int r = 0; r < 4; ++r) {
            f4 x = ld4(vb + (size_t)(h + r * 8) * C_ + c4 * 4);
            acc += x;
        }
        __shared__ f4 red[256];
        red[t] = acc;
        __syncthreads();
        if (t < 32) {
            f4 s = red[t];
#pragma unroll
            for (int i = 1; i < 8; ++i) s += red[i * 32 + t];
            *((f4*)(vsum_part + (size_t)g * C_) + t) = s;
        }
    } else {
        // ---- a[r]=q·(Wq@w1), kb[r]=k·(Wk@w1) ; 1024 blocks x 32 rows ----
        int gg = g - 1024;
        int b_r0 = gg * 32;                   // global row base (b*N+n flattened)
        __shared__ float wq1l[C_], wk1l[C_];
        if (t < C_) {
            float s = 0.f;
            for (int c2 = 0; c2 < CN_; ++c2) s += Wq[t * CN_ + c2] * w1[c2];
            wq1l[t] = s;
        } else {
            int c = t - C_;
            float s = 0.f;
            for (int c2 = 0; c2 < CN_; ++c2) s += Wk[c * CN_ + c2] * w1[c2];
            wk1l[c] = s;
        }
        __syncthreads();
        int lane = t & 63, wv = t >> 6;
        int grp = lane >> 4, li = lane & 15;
        f4 wq0 = *((const f4*)wq1l + li * 2);
        f4 wq1v = *((const f4*)wq1l + li * 2 + 1);
        f4 wk0 = *((const f4*)wk1l + li * 2);
        f4 wk1v = *((const f4*)wk1l + li * 2 + 1);
        int r0 = b_r0 + wv * 8;
#pragma unroll
        for (int it = 0; it < 2; ++it) {
            int r = r0 + it * 4 + grp;
            const float* qr = q + (size_t)r * C_;
            const float* kr = k + (size_t)r * C_;
            f4 x0 = ld4(qr + li * 8), x1 = ld4(qr + li * 8 + 4);
            f4 y0 = ld4(kr + li * 8), y1 = ld4(kr + li * 8 + 4);
            float ta = x0.x * wq0.x + x0.y * wq0.y + x0.z * wq0.z + x0.w * wq0.w
                     + x1.x * wq1v.x + x1.y * wq1v.y + x1.z * wq1v.z + x1.w * wq1v.w;
            float tk = y0.x * wk0.x + y0.y * wk0.y + y0.z * wk0.z + y0.w * wk0.w
                     + y1.x * wk1v.x + y1.y * wk1v.y + y1.z * wk1v.z + y1.w * wk1v.w;
            ta = red16_add(ta);
            tk = red16_add(tk);
            if (li == 0) { a_ws[r] = ta; kb_ws[r] = tk; }
        }
    }
}

// ================= kPE: 512 thr, 8 waves = (4 row-groups x 2 m-halves), 32 waves/CU =================
__global__ __launch_bounds__(512, 8) void kPE(const float* __restrict__ pe,
                                              const float* __restrict__ w1,
                                              float* __restrict__ pdot,
                                              float* __restrict__ pe_part) {
    int g = blockIdx.x;            // 1024 blocks: 256 per b, 32 rows each
    int b = g >> 8;
    int r0 = (g & 255) * 32;
    int t = threadIdx.x;
    int lane = t & 63, wv = t >> 6;      // 8 waves
    int rw = wv >> 1, h = wv & 1;        // row-group, m-half
    int grp = lane >> 4, li = lane & 15;
    f4 w1v = *((const f4*)w1 + li);

    __shared__ float lpd[32][32];        // 4 KB: [row_local][m]
    __shared__ f4 buf[8][256];           // 32 KB

    f4 acc0 = (f4){0.f,0.f,0.f,0.f}, acc1 = acc0, acc2 = acc0, acc3 = acc0;

    const float* pw = pe + ((size_t)(b * N_ + r0 + rw * 8)) * (M_ * CN_) + h * 1024 + lane * 4;
#pragma unroll 2
    for (int i = 0; i < 8; ++i) {
        f4 x0 = ld4(pw);
        f4 x1 = ld4(pw + 256);
        f4 x2 = ld4(pw + 512);
        f4 x3 = ld4(pw + 768);
        acc0 += x0; acc1 += x1; acc2 += x2; acc3 += x3;
        float t0 = x0.x * w1v.x + x0.y * w1v.y + x0.z * w1v.z + x0.w * w1v.w;
        float t1 = x1.x * w1v.x + x1.y * w1v.y + x1.z * w1v.z + x1.w * w1v.w;
        float t2 = x2.x * w1v.x + x2.y * w1v.y + x2.z * w1v.z + x2.w * w1v.w;
        float t3 = x3.x * w1v.x + x3.y * w1v.y + x3.z * w1v.z + x3.w * w1v.w;
        t0 = red16_add(t0);
        t1 = red16_add(t1);
        t2 = red16_add(t2);
        t3 = red16_add(t3);
        if (li == 0) {
            int rl = rw * 8 + i;
            lpd[rl][h * 16 + grp]      = t0;
            lpd[rl][h * 16 + 4 + grp]  = t1;
            lpd[rl][h * 16 + 8 + grp]  = t2;
            lpd[rl][h * 16 + 12 + grp] = t3;
        }
        pw += M_ * CN_;
    }
    buf[wv][lane]       = acc0;
    buf[wv][64 + lane]  = acc1;
    buf[wv][128 + lane] = acc2;
    buf[wv][192 + lane] = acc3;
    __syncthreads();
    // pdot writeback: 1024 floats, coalesced
    {
        float* pout = pdot + ((size_t)b * N_ + r0) * M_;
        const float* lf = &lpd[0][0];
        pout[t] = lf[t];
        pout[512 + t] = lf[512 + t];
    }
    // pe_part: combine the 4 row-group waves per m-half
    {
        f4* ppg = (f4*)(pe_part + (size_t)g * (M_ * CN_));
        int hs = t >> 8, idx = t & 255;
        f4 r = buf[hs][idx] + buf[2 + hs][idx] + buf[4 + hs][idx] + buf[6 + hs][idx];
        ppg[t] = r;
    }
}

// ================= kB: SW2 = ((vsum-excl)@Wv + sum_partials) @ w_sa2 =================
__global__ __launch_bounds__(256) void kB(const float* __restrict__ v,
                                          const float* __restrict__ Wv,
                                          const float* __restrict__ vsum_part,
                                          const float* __restrict__ pe_part,
                                          const float* __restrict__ w2,
                                          float* __restrict__ SW2) {
    int b = blockIdx.x >> 3, seg = blockIdx.x & 7;   // 32 blocks
    int t = threadIdx.x;
    __shared__ float vsum[C_];
    __shared__ float vd[4][C_];
    __shared__ float Sl[4][CN_];
    if (t < C_) {
        float s = 0.f;
        const float* vp = vsum_part + (size_t)b * 256 * C_ + t;
        for (int i = 0; i < 256; ++i) s += vp[i * C_];
        vsum[t] = s;
    }
    __syncthreads();
#pragma unroll
    for (int mlp = 0; mlp < 2; ++mlp) {
        int ml = (t >> 7) + mlp * 2;
        int c = t & 127;
        int m = seg * 4 + ml;
        float excl = 0.f;
        if (m > 16) {
            for (int r = 0; r < m - 16; ++r) excl += v[((size_t)b * N_ + r) * C_ + c];
        } else if (m < 16) {
            for (int r = N_ - (16 - m); r < N_; ++r) excl += v[((size_t)b * N_ + r) * C_ + c];
        }
        vd[ml][c] = vsum[c] - excl;
    }
    __syncthreads();
    {
        int ml = t >> 6, c2 = t & 63;
        float s = 0.f;
        for (int c = 0; c < C_; ++c) s += vd[ml][c] * Wv[c * CN_ + c2];
        const float* pp = pe_part + (size_t)b * 256 * (M_ * CN_) + seg * 256 + t;
        float a0 = 0.f, a1 = 0.f, a2 = 0.f, a3 = 0.f;
        for (int p = 0; p < 256; p += 4) {
            a0 += pp[(size_t)(p + 0) * (M_ * CN_)];
            a1 += pp[(size_t)(p + 1) * (M_ * CN_)];
            a2 += pp[(size_t)(p + 2) * (M_ * CN_)];
            a3 += pp[(size_t)(p + 3) * (M_ * CN_)];
        }
        s += (a0 + a1) + (a2 + a3);
        Sl[ml][c2] = s;
    }
    __syncthreads();
#pragma unroll
    for (int pass = 0; pass < 2; ++pass) {
        int ml = (t >> 7) + pass * 2;
        int cc = t & 127;
        float s = 0.f;
#pragma unroll
        for (int c2 = 0; c2 < CN_; ++c2) s += Sl[ml][c2] * w2[c2 * C_ + cc];
        SW2[((size_t)b * M_ + seg * 4 + ml) * C_ + cc] = s;
    }
}

// ================= kOut: softmax -> LDS ; out = scores @ SW2 (regs) =================
__global__ __launch_bounds__(256, 4) void kOut(const float* __restrict__ pdot,
                                               const float* __restrict__ a_ws,
                                               const float* __restrict__ kb_ws,
                                               const float* __restrict__ SW2,
                                               float* __restrict__ out) {
    int g = blockIdx.x;        // 1024 blocks: 256 per b, 32 rows each
    int b = g >> 8;
    int n0 = (g & 255) * 32;
    int t = threadIdx.x;
    int lane = t & 63, wv = t >> 6;
    __shared__ float scl[32][M_];   // 4 KB

    {
        int hw = t >> 5, m = t & 31;
        const float* kbb = kb_ws + (size_t)b * N_;
#pragma unroll
        for (int i = 0; i < 4; ++i) {
            int r = i * 8 + hw;
            int n = n0 + r;
            size_t u = (size_t)b * N_ + (size_t)n;
            float pd = pdot[u * M_ + m];
            int j = n + m - 16;
            float kbm = (j >= 0 && j < N_) ? kbb[j] : 0.f;
            float lg = a_ws[u] + pd - kbm;
            float mx = dpp_max<ROR1>(dpp_max<ROR2>(dpp_max<ROR4>(dpp_max<ROR8>(lg))));
            mx = fmaxf(mx, __shfl_xor(mx, 16));
            float e = __expf(lg - mx);
            float sm = red16_add(e);
            sm += __shfl_xor(sm, 16);
            scl[r][m] = e / sm;
        }
    }
    f2 sw2[M_];
    {
        const f2* sw2g = (const f2*)(SW2 + (size_t)b * M_ * C_);
#pragma unroll
        for (int mm = 0; mm < M_; ++mm) sw2[mm] = sw2g[mm * 64 + lane];
    }
    __syncthreads();
#pragma unroll
    for (int i = 0; i < 8; ++i) {
        int r = wv * 8 + i;
        const f4* sp = (const f4*)(&scl[r][0]);
        float ox = 0.f, oy = 0.f;
#pragma unroll
        for (int j4 = 0; j4 < 8; ++j4) {
            f4 s4 = sp[j4];
            ox += s4.x * sw2[j4 * 4 + 0].x; oy += s4.x * sw2[j4 * 4 + 0].y;
            ox += s4.y * sw2[j4 * 4 + 1].x; oy += s4.y * sw2[j4 * 4 + 1].y;
            ox += s4.z * sw2[j4 * 4 + 2].x; oy += s4.z * sw2[j4 * 4 + 2].y;
            ox += s4.w * sw2[j4 * 4 + 3].x; oy += s4.w * sw2[j4 * 4 + 3].y;
        }
        size_t u = (size_t)b * N_ + (size_t)(n0 + r);
        f2 o; o.x = ox; o.y = oy;
        *((f2*)(out + u * C_) + lane) = o;
    }
}

extern "C" void kernel_launch(void* const* d_in, const int* in_sizes, int n_in,
                              void* d_out, int out_size, void* d_ws, size_t ws_size,
                              hipStream_t stream) {
    const float* q  = (const float*)d_in[0];
    const float* k  = (const float*)d_in[1];
    const float* v  = (const float*)d_in[2];
    const float* pe = (const float*)d_in[3];
    const float* Wq = (const float*)d_in[4];
    const float* Wk = (const float*)d_in[5];
    const float* Wv = (const float*)d_in[6];
    const float* w1 = (const float*)d_in[7];
    const float* w2 = (const float*)d_in[8];
    float* out = (float*)d_out;
    float* ws  = (float*)d_ws;

    // workspace layout (floats)
    float* vsum_part = ws;                          // 1024*128  = 131072
    float* a_ws      = vsum_part + 131072;          // 32768
    float* kb_ws     = a_ws + 32768;                // 32768
    float* pdot      = kb_ws + 32768;               // 4*8192*32 = 1048576
    float* pe_part   = pdot + 1048576;              // 1024*2048 = 2097152
    float* SW2       = pe_part + 2097152;           // 4*32*128  = 16384

    k1  <<<2048, 256, 0, stream>>>(q, k, v, Wq, Wk, w1, vsum_part, a_ws, kb_ws);
    kPE <<<1024, 512, 0, stream>>>(pe, w1, pdot, pe_part);
    kB  <<<32, 256, 0, stream>>>(v, Wv, vsum_part, pe_part, w2, SW2);
    kOut<<<1024, 256, 0, stream>>>(pdot, a_ws, kb_ws, SW2, out);
}

// Round 8
// 98.590 us; speedup vs baseline: 1.2904x; 1.2904x over previous
//
#include <hip/hip_runtime.h>
#include <math.h>

#define B_ 4
#define N_ 8192
#define C_ 128
#define CN_ 64
#define M_ 32

#define ROR1 0x121
#define ROR2 0x122
#define ROR4 0x124
#define ROR8 0x128

typedef float f4 __attribute__((ext_vector_type(4)));
typedef float f2 __attribute__((ext_vector_type(2)));

__device__ __forceinline__ f4 ld4(const float* p) { return *(const f4*)p; }

template<int CTRL>
__device__ __forceinline__ float dpp_add(float x) {
    int y = __builtin_amdgcn_update_dpp(0, __float_as_int(x), CTRL, 0xF, 0xF, true);
    return x + __int_as_float(y);
}
template<int CTRL>
__device__ __forceinline__ float dpp_max(float x) {
    int y = __builtin_amdgcn_update_dpp(0, __float_as_int(x), CTRL, 0xF, 0xF, true);
    return fmaxf(x, __int_as_float(y));
}
__device__ __forceinline__ float red16_add(float x) {
    return dpp_add<ROR1>(dpp_add<ROR2>(dpp_add<ROR4>(dpp_add<ROR8>(x))));
}
__device__ __forceinline__ float red16_max(float x) {
    return dpp_max<ROR1>(dpp_max<ROR2>(dpp_max<ROR4>(dpp_max<ROR8>(x))));
}

// ================= k1: vsum partials (0..255) + a/kb rows (256..511) — R6-identical =================
__global__ __launch_bounds__(256) void k1(const float* __restrict__ q,
                                          const float* __restrict__ k,
                                          const float* __restrict__ v,
                                          const float* __restrict__ Wq,
                                          const float* __restrict__ Wk,
                                          const float* __restrict__ w1,
                                          float* __restrict__ vsum_part,
                                          float* __restrict__ a_ws,
                                          float* __restrict__ kb_ws) {
    int g = blockIdx.x;
    int t = threadIdx.x;
    if (g < 256) {
        int b = g >> 6;
        int chunk = g & 63;
        const float* vb = v + ((size_t)b * N_ + (size_t)chunk * 128) * C_;
        int c4 = t & 31, h = t >> 5;
        f4 acc = (f4){0.f, 0.f, 0.f, 0.f};
        for (int r = h; r < 128; r += 8) acc += ld4(vb + (size_t)r * C_ + c4 * 4);
        __shared__ f4 red[256];
        red[t] = acc;
        __syncthreads();
        if (t < 32) {
            f4 s = red[t];
#pragma unroll
            for (int i = 1; i < 8; ++i) s += red[i * 32 + t];
            *((f4*)(vsum_part + (size_t)g * C_) + t) = s;
        }
    } else {
        int gg = g - 256;
        __shared__ float wq1l[C_], wk1l[C_];
        if (t < C_) {
            float s = 0.f;
            for (int c2 = 0; c2 < CN_; ++c2) s += Wq[t * CN_ + c2] * w1[c2];
            wq1l[t] = s;
        } else {
            int c = t - C_;
            float s = 0.f;
            for (int c2 = 0; c2 < CN_; ++c2) s += Wk[c * CN_ + c2] * w1[c2];
            wk1l[c] = s;
        }
        __syncthreads();
        int lane = t & 63, wv = t >> 6;
        int grp = lane >> 4, li = lane & 15;
        f4 wq0 = *((const f4*)wq1l + li * 2);
        f4 wq1v = *((const f4*)wq1l + li * 2 + 1);
        f4 wk0 = *((const f4*)wk1l + li * 2);
        f4 wk1v = *((const f4*)wk1l + li * 2 + 1);
        int r0 = gg * 128 + wv * 32;
        for (int it = 0; it < 8; ++it) {
            int r = r0 + it * 4 + grp;
            const float* qr = q + (size_t)r * C_;
            const float* kr = k + (size_t)r * C_;
            f4 x0 = ld4(qr + li * 8), x1 = ld4(qr + li * 8 + 4);
            f4 y0 = ld4(kr + li * 8), y1 = ld4(kr + li * 8 + 4);
            float ta = x0.x * wq0.x + x0.y * wq0.y + x0.z * wq0.z + x0.w * wq0.w
                     + x1.x * wq1v.x + x1.y * wq1v.y + x1.z * wq1v.z + x1.w * wq1v.w;
            float tk = y0.x * wk0.x + y0.y * wk0.y + y0.z * wk0.z + y0.w * wk0.w
                     + y1.x * wk1v.x + y1.y * wk1v.y + y1.z * wk1v.z + y1.w * wk1v.w;
            ta = red16_add(ta);
            tk = red16_add(tk);
            if (li == 0) { a_ws[r] = ta; kb_ws[r] = tk; }
        }
    }
}

// ================= kPE: pe stream (R6 structure) + fused softmax -> scores =================
__global__ __launch_bounds__(256) void kPE(const float* __restrict__ pe,
                                           const float* __restrict__ w1,
                                           const float* __restrict__ a_ws,
                                           const float* __restrict__ kb_ws,
                                           float* __restrict__ scl_g,
                                           float* __restrict__ pe_part) {
    int g = blockIdx.x;           // 1024 blocks: 256 per b, 32 rows each
    int b = g >> 8;
    int n0 = (g & 255) * 32;
    int t = threadIdx.x;
    int lane = t & 63, wv = t >> 6;
    int grp = lane >> 4, li = lane & 15;
    f4 w1v = *((const f4*)w1 + li);

    __shared__ float lpd[4][256];    // 4 KB pdot staging
    __shared__ f4 lps4[4][256];      // 16 KB half-reduce buffer

    f4 acc[8];
#pragma unroll
    for (int j = 0; j < 8; ++j) acc[j] = (f4){0.f, 0.f, 0.f, 0.f};

    int nbase = n0 + wv * 8;
    const float* pbase = pe + ((size_t)b * N_ + (size_t)nbase) * (size_t)(M_ * CN_);
    for (int i = 0; i < 8; ++i) {
        const float* p = pbase + (size_t)i * (M_ * CN_);
        f4 x[8];
#pragma unroll
        for (int j = 0; j < 8; ++j) x[j] = ld4(p + (j * 64 + lane) * 4);
#pragma unroll
        for (int j = 0; j < 8; ++j) {
            acc[j] += x[j];
            float tv = x[j].x * w1v.x + x[j].y * w1v.y + x[j].z * w1v.z + x[j].w * w1v.w;
            tv = red16_add(tv);
            if (li == 0) lpd[wv][i * 32 + j * 4 + grp] = tv;
        }
    }
    // fused softmax: half-wave per row, 4 iterations; store scores (wave-local lpd read)
    {
        int hw = lane >> 5, m = lane & 31;
        const float* kbb = kb_ws + (size_t)b * N_;
        float* sout = scl_g + ((size_t)b * N_ + (size_t)nbase) * M_;
#pragma unroll
        for (int ii = 0; ii < 4; ++ii) {
            int rl = ii * 2 + hw;
            int n = nbase + rl;
            float pd = lpd[wv][rl * 32 + m];
            int j = n + m - 16;
            float kbm = (j >= 0 && j < N_) ? kbb[j] : 0.f;
            float lg = a_ws[(size_t)b * N_ + n] + pd - kbm;
            float mx = red16_max(lg);
            mx = fmaxf(mx, __shfl_xor(mx, 16));
            float e = __expf(lg - mx);
            float sm = red16_add(e);
            sm += __shfl_xor(sm, 16);
            sout[ii * 64 + lane] = e / sm;   // (ii*2+hw)*32 + m == ii*64 + lane
        }
    }
    // cross-wave reduce in two 16KB rounds -> pe_part[g]
    f4* ppg = (f4*)(pe_part + (size_t)g * (M_ * CN_));
#pragma unroll
    for (int r = 0; r < 2; ++r) {
        __syncthreads();
#pragma unroll
        for (int jr = 0; jr < 4; ++jr) lps4[wv][jr * 64 + lane] = acc[r * 4 + jr];
        __syncthreads();
        f4 s = lps4[0][t];
        s += lps4[1][t];
        s += lps4[2][t];
        s += lps4[3][t];
        ppg[r * 256 + t] = s;
    }
}

// ================= kR: parallel reduce: S_sum[b,2048] over 256 partials ; vsum_final =================
__global__ __launch_bounds__(256) void kR(const float* __restrict__ pe_part,
                                          const float* __restrict__ vsum_part,
                                          float* __restrict__ S_sum,
                                          float* __restrict__ vsum_final) {
    int g = blockIdx.x;
    int t = threadIdx.x;
    if (g < 256) {
        int b = g >> 6, ch = g & 63;        // 32-float chunk
        int pg = t >> 5, fi = t & 31;
        const float* base = pe_part + (size_t)b * 256 * 2048 + ch * 32 + fi;
        float a0 = 0.f, a1 = 0.f, a2 = 0.f, a3 = 0.f;
#pragma unroll
        for (int p = pg; p < 256; p += 32) {
            a0 += base[(size_t)p * 2048];
            a1 += base[(size_t)(p + 8) * 2048];
            a2 += base[(size_t)(p + 16) * 2048];
            a3 += base[(size_t)(p + 24) * 2048];
        }
        __shared__ float red[8][32];
        red[pg][fi] = (a0 + a1) + (a2 + a3);
        __syncthreads();
        if (t < 32) {
            float s = red[0][t];
#pragma unroll
            for (int i = 1; i < 8; ++i) s += red[i][t];
            S_sum[(size_t)b * 2048 + ch * 32 + t] = s;
        }
    } else {
        int b = g - 256;
        if (t < C_) {
            const float* vp = vsum_part + (size_t)b * 64 * C_ + t;
            float a0 = 0.f, a1 = 0.f, a2 = 0.f, a3 = 0.f;
#pragma unroll
            for (int i = 0; i < 64; i += 4) {
                a0 += vp[(i + 0) * C_];
                a1 += vp[(i + 1) * C_];
                a2 += vp[(i + 2) * C_];
                a3 += vp[(i + 3) * C_];
            }
            vsum_final[b * C_ + t] = (a0 + a1) + (a2 + a3);
        }
    }
}

// ================= kB2: SW2 = ((vsum-excl)@Wv + S_sum) @ w_sa2 =================
__global__ __launch_bounds__(256) void kB2(const float* __restrict__ v,
                                           const float* __restrict__ Wv,
                                           const float* __restrict__ vsum_final,
                                           const float* __restrict__ S_sum,
                                           const float* __restrict__ w2,
                                           float* __restrict__ SW2) {
    int b = blockIdx.x >> 3, seg = blockIdx.x & 7;   // 32 blocks
    int t = threadIdx.x;
    __shared__ float vd[4][C_];
    __shared__ float Sl[4][CN_];
#pragma unroll
    for (int mlp = 0; mlp < 2; ++mlp) {
        int ml = (t >> 7) + mlp * 2;
        int c = t & 127;
        int m = seg * 4 + ml;
        float excl = 0.f;
        if (m > 16) {
            for (int r = 0; r < m - 16; ++r) excl += v[((size_t)b * N_ + r) * C_ + c];
        } else if (m < 16) {
            for (int r = N_ - (16 - m); r < N_; ++r) excl += v[((size_t)b * N_ + r) * C_ + c];
        }
        vd[ml][c] = vsum_final[b * C_ + c] - excl;
    }
    __syncthreads();
    {
        int ml = t >> 6, c2 = t & 63;
        float s = 0.f;
        for (int c = 0; c < C_; ++c) s += vd[ml][c] * Wv[c * CN_ + c2];
        s += S_sum[(size_t)b * 2048 + (seg * 4 + ml) * CN_ + c2];
        Sl[ml][c2] = s;
    }
    __syncthreads();
#pragma unroll
    for (int pass = 0; pass < 2; ++pass) {
        int ml = (t >> 7) + pass * 2;
        int cc = t & 127;
        float s = 0.f;
#pragma unroll
        for (int c2 = 0; c2 < CN_; ++c2) s += Sl[ml][c2] * w2[c2 * C_ + cc];
        SW2[((size_t)b * M_ + seg * 4 + ml) * C_ + cc] = s;
    }
}

// ================= kOut2: out = scores @ SW2 (scores staged via LDS, SW2 in regs) =================
__global__ __launch_bounds__(256) void kOut2(const float* __restrict__ scl_g,
                                             const float* __restrict__ SW2,
                                             float* __restrict__ out) {
    int g = blockIdx.x;        // 512 blocks: 128 per b, 64 rows each
    int b = g >> 7;
    int n0 = (g & 127) * 64;
    int t = threadIdx.x;
    int lane = t & 63, wv = t >> 6;
    __shared__ float scl[64][M_];   // 8 KB

    {
        const f4* src = (const f4*)(scl_g + ((size_t)b * N_ + (size_t)n0) * M_);
        f4* dst = (f4*)&scl[0][0];
        dst[t] = src[t];
        dst[256 + t] = src[256 + t];
    }
    f2 sw2[M_];
    {
        const f2* sw2g = (const f2*)(SW2 + (size_t)b * M_ * C_);
#pragma unroll
        for (int mm = 0; mm < M_; ++mm) sw2[mm] = sw2g[mm * 64 + lane];
    }
    __syncthreads();
    for (int i = 0; i < 16; ++i) {
        int r = wv * 16 + i;
        const f4* sp = (const f4*)(&scl[r][0]);
        float ox = 0.f, oy = 0.f;
#pragma unroll
        for (int j4 = 0; j4 < 8; ++j4) {
            f4 s4 = sp[j4];
            ox += s4.x * sw2[j4 * 4 + 0].x; oy += s4.x * sw2[j4 * 4 + 0].y;
            ox += s4.y * sw2[j4 * 4 + 1].x; oy += s4.y * sw2[j4 * 4 + 1].y;
            ox += s4.z * sw2[j4 * 4 + 2].x; oy += s4.z * sw2[j4 * 4 + 2].y;
            ox += s4.w * sw2[j4 * 4 + 3].x; oy += s4.w * sw2[j4 * 4 + 3].y;
        }
        size_t u = (size_t)b * N_ + (size_t)(n0 + r);
        f2 o; o.x = ox; o.y = oy;
        *((f2*)(out + u * C_) + lane) = o;
    }
}

extern "C" void kernel_launch(void* const* d_in, const int* in_sizes, int n_in,
                              void* d_out, int out_size, void* d_ws, size_t ws_size,
                              hipStream_t stream) {
    const float* q  = (const float*)d_in[0];
    const float* k  = (const float*)d_in[1];
    const float* v  = (const float*)d_in[2];
    const float* pe = (const float*)d_in[3];
    const float* Wq = (const float*)d_in[4];
    const float* Wk = (const float*)d_in[5];
    const float* Wv = (const float*)d_in[6];
    const float* w1 = (const float*)d_in[7];
    const float* w2 = (const float*)d_in[8];
    float* out = (float*)d_out;
    float* ws  = (float*)d_ws;

    // workspace layout (floats)
    float* vsum_part  = ws;                          // 256*128   = 32768
    float* vsum_final = vsum_part + 32768;           // 512
    float* a_ws       = vsum_final + 512;            // 32768
    float* kb_ws      = a_ws + 32768;                // 32768
    float* scl_g      = kb_ws + 32768;               // 4*8192*32 = 1048576
    float* pe_part    = scl_g + 1048576;             // 1024*2048 = 2097152
    float* S_sum      = pe_part + 2097152;           // 8192
    float* SW2        = S_sum + 8192;                // 16384

    k1   <<<512, 256, 0, stream>>>(q, k, v, Wq, Wk, w1, vsum_part, a_ws, kb_ws);
    kPE  <<<1024, 256, 0, stream>>>(pe, w1, a_ws, kb_ws, scl_g, pe_part);
    kR   <<<260, 256, 0, stream>>>(pe_part, vsum_part, S_sum, vsum_final);
    kB2  <<<32, 256, 0, stream>>>(v, Wv, vsum_final, S_sum, w2, SW2);
    kOut2<<<512, 256, 0, stream>>>(scl_g, SW2, out);
}